// Round 7
// baseline (630.845 us; speedup 1.0000x reference)
//
#include <hip/hip_runtime.h>
#include <math.h>

#define NB 2048
#define NS 512
#define ND 96

typedef __attribute__((ext_vector_type(8))) short short8;
typedef __attribute__((ext_vector_type(4))) float floatx4;

__device__ __forceinline__ float sigm(float x) {
    return 1.0f / (1.0f + __expf(-x));
}
// fp32x8 -> bf16x8 via hardware packed convert (RNE), 4 instructions.
__device__ __forceinline__ short8 cvt8(floatx4 p0, floatx4 p1) {
    union { unsigned u[4]; short8 s; } r;
    asm("v_cvt_pk_bf16_f32 %0, %1, %2" : "=v"(r.u[0]) : "v"(p0[0]), "v"(p0[1]));
    asm("v_cvt_pk_bf16_f32 %0, %1, %2" : "=v"(r.u[1]) : "v"(p0[2]), "v"(p0[3]));
    asm("v_cvt_pk_bf16_f32 %0, %1, %2" : "=v"(r.u[2]) : "v"(p1[0]), "v"(p1[1]));
    asm("v_cvt_pk_bf16_f32 %0, %1, %2" : "=v"(r.u[3]) : "v"(p1[2]), "v"(p1[3]));
    return r.s;
}

// Empirical reg-cap mapping on this toolchain: cap = 2048/(waves_per_block*N).
// (512,4)->64 SPILL(old 24-reg acc6 layout), (512,2)->128 ok, clean.
// Evidence from the round-3 spill run: 32 waves/CU sustains 3.46 TB/s on this
// access pattern; 16 waves/CU only ~2.1 TB/s. So target 64 regs WITHOUT spill:
// two-pass tile (scores first, recompute seq_h via MFMA for the weighted sum)
// keeps peak live state ~55 regs. (256,8) -> cap 64, 8 blocks/CU, whole grid
// resident (2048 blocks = 8 x 256 CUs).
__global__ __launch_bounds__(256, 8)
void attn_fused(const float* __restrict__ seq,   // (B,S,96)
                const float* __restrict__ tgt,   // (B,1,96)
                const int*   __restrict__ mask,  // (B,513,1) int32
                const float* __restrict__ w1,    // (96,96) [e][d]
                const float* __restrict__ b1,    // (96)
                const float* __restrict__ w2,    // (96,96) [e][d]
                const float* __restrict__ b2,    // (96)
                float* __restrict__ out)         // (B,96)
{
    // W1 staged as bf16 MFMA B-fragments: frag(t,kk) for lane L at
    // w1f[((t*3+kk)*64 + L)*8 .. +8]  — ds_read_b128, conflict-free.
    // LDS total 20368 B <= 20 KB so 8 blocks/CU fit (160 KB / 8).
    __shared__ short w1f[18 * 64 * 8];           // 18432 B
    __shared__ float th[ND];                     // 384 B  (tgt_h incl b2)
    __shared__ float red2[4];                    // 16 B
    __shared__ float osum[4][ND];                // 1536 B

    const int b    = blockIdx.x;
    const int tid  = threadIdx.x;
    const int lane = tid & 63;
    const int wave = tid >> 6;                   // 0..3
    const int l15  = lane & 15;
    const int quad = lane >> 4;

    // ---- stage W1 -> bf16 fragments in LDS ----
    for (int idx = tid; idx < 1152; idx += 256) {   // 96 rows x 12 chunks of 8
        const int e  = idx / 12;
        const int dc = idx - 12 * e;
        const int kk = dc >> 2;
        const int q  = dc & 3;
        const float* p = w1 + e * ND + kk * 32 + q * 8;
        floatx4 p0 = *(const floatx4*)(p);
        floatx4 p1 = *(const floatx4*)(p + 4);
        const int t = e >> 4, r = e & 15;
        *(short8*)&w1f[(((t * 3 + kk) * 64) + q * 16 + r) * 8] = cvt8(p0, p1);
    }

    // ---- tgt_h: 96 threads, one e each (incl. b2) ----
    if (tid < ND) {
        const float* tv = tgt + (size_t)b * ND;
        const float* wr = w2 + tid * ND;
        float a0 = 0.f, a1 = 0.f;
        #pragma unroll
        for (int d = 0; d < ND; d += 8) {
            floatx4 x0 = *(const floatx4*)(tv + d);
            floatx4 w0 = *(const floatx4*)(wr + d);
            floatx4 x1 = *(const floatx4*)(tv + d + 4);
            floatx4 w1v = *(const floatx4*)(wr + d + 4);
            a0 += x0[0]*w0[0] + x0[1]*w0[1] + x0[2]*w0[2] + x0[3]*w0[3];
            a1 += x1[0]*w1v[0] + x1[1]*w1v[1] + x1[2]*w1v[2] + x1[3]*w1v[3];
        }
        th[tid] = b2[tid] + a0 + a1;
    }
    __syncthreads();

    float tgtv[6], biasv[6];
    #pragma unroll
    for (int t = 0; t < 6; ++t) {
        const int e = 16 * t + l15;
        tgtv[t]  = th[e];
        biasv[t] = b1[e];
    }

    // ---- fused main loop: each of 4 waves owns 8 s-tiles of 16 rows.
    // Two passes per tile (register-lean):
    //   pass 1: seq_h via MFMA (acc transient), scores = sum sigmoid,
    //           butterfly, e_r = mask * exp(score-48)  (fixed shift; softmax
    //           is shift-invariant, scores in (0,96))
    //   pass 2: RECOMPUTE seq_h via the identical MFMA chain (matrix pipe is
    //           ~2% utilized — trade MFMA for 24 fewer live VGPRs) and fold
    //           the weighted output sum. Bitwise-identical result.
    const float* abase = seq + ((size_t)b * NS + l15) * ND + quad * 8;
    const int*   mbase = mask + (size_t)b * (NS + 1) + quad * 4;
    float o_acc[6] = {0.f, 0.f, 0.f, 0.f, 0.f, 0.f};
    float sacc = 0.f;      // Σ e over this quad's rows (dup across l15)

    #pragma unroll 1
    for (int sti = 0; sti < 8; ++sti) {
        const int s0 = (wave * 8 + sti) * 16;
        union { short8 s; unsigned u[4]; } afu[3];
        #pragma unroll
        for (int kk = 0; kk < 3; ++kk) {
            const float* p = abase + (size_t)s0 * ND + kk * 32;
            afu[kk].s = cvt8(*(const floatx4*)(p), *(const floatx4*)(p + 4));
        }
        // mask for this quad's 4 rows (base not 16B-aligned for odd b -> 4 scalar loads)
        const int mk0 = mbase[s0 + 0];
        const int mk1 = mbase[s0 + 1];
        const int mk2 = mbase[s0 + 2];
        const int mk3 = mbase[s0 + 3];

        // ---- pass 1: scores ----
        float p0s = 0.f, p1s = 0.f, p2s = 0.f, p3s = 0.f;
        #pragma unroll
        for (int t = 0; t < 6; ++t) {
            floatx4 acc = { biasv[t], biasv[t], biasv[t], biasv[t] };
            #pragma unroll
            for (int kk = 0; kk < 3; ++kk) {
                const short8 bf = *(const short8*)&w1f[((t * 3 + kk) * 64 + lane) * 8];
                acc = __builtin_amdgcn_mfma_f32_16x16x32_bf16(afu[kk].s, bf, acc, 0, 0, 0);
            }
            const float thv = tgtv[t];
            p0s += sigm(acc[0] + thv);
            p1s += sigm(acc[1] + thv);
            p2s += sigm(acc[2] + thv);
            p3s += sigm(acc[3] + thv);
        }
        #pragma unroll
        for (int off = 1; off < 16; off <<= 1) {
            p0s += __shfl_xor(p0s, off, 64);
            p1s += __shfl_xor(p1s, off, 64);
            p2s += __shfl_xor(p2s, off, 64);
            p3s += __shfl_xor(p3s, off, 64);
        }
        const float e0 = (mk0 != 0) ? 0.f : __expf(p0s - 48.f);
        const float e1 = (mk1 != 0) ? 0.f : __expf(p1s - 48.f);
        const float e2 = (mk2 != 0) ? 0.f : __expf(p2s - 48.f);
        const float e3 = (mk3 != 0) ? 0.f : __expf(p3s - 48.f);
        sacc += e0 + e1 + e2 + e3;

        // opaque touch: keeps af live here and blocks CSE of the second MFMA
        // chain with the first (CSE would resurrect 24 live acc registers).
        #pragma unroll
        for (int kk = 0; kk < 3; ++kk) {
            asm volatile("" : "+v"(afu[kk].u[0]), "+v"(afu[kk].u[1]),
                              "+v"(afu[kk].u[2]), "+v"(afu[kk].u[3]));
        }

        // ---- pass 2: recompute seq_h, weighted accumulate ----
        #pragma unroll
        for (int t = 0; t < 6; ++t) {
            floatx4 acc = { biasv[t], biasv[t], biasv[t], biasv[t] };
            #pragma unroll
            for (int kk = 0; kk < 3; ++kk) {
                const short8 bf = *(const short8*)&w1f[((t * 3 + kk) * 64 + lane) * 8];
                acc = __builtin_amdgcn_mfma_f32_16x16x32_bf16(afu[kk].s, bf, acc, 0, 0, 0);
            }
            o_acc[t] += e0 * acc[0] + e1 * acc[1] + e2 * acc[2] + e3 * acc[3];
        }
    }

    // ---- denominator: sacc identical across the 16 l15 lanes of a quad;
    // xor-16/32 sums the 4 quads exactly once ----
    float ss = sacc;
    ss += __shfl_xor(ss, 16, 64);
    ss += __shfl_xor(ss, 32, 64);
    if (lane == 0) red2[wave] = ss;

    // ---- output reduce: sum quads in-wave, then waves via LDS ----
    #pragma unroll
    for (int t = 0; t < 6; ++t) {
        o_acc[t] += __shfl_xor(o_acc[t], 16, 64);
        o_acc[t] += __shfl_xor(o_acc[t], 32, 64);
    }
    if (quad == 0) {
        #pragma unroll
        for (int t = 0; t < 6; ++t) osum[wave][16 * t + l15] = o_acc[t];
    }
    __syncthreads();
    if (tid < ND) {
        const float tot = red2[0] + red2[1] + red2[2] + red2[3];
        float a = 0.f;
        #pragma unroll
        for (int w = 0; w < 4; ++w) a += osum[w][tid];
        out[(size_t)b * ND + tid] = a * (1.0f / tot);
    }
}

extern "C" void kernel_launch(void* const* d_in, const int* in_sizes, int n_in,
                              void* d_out, int out_size, void* d_ws, size_t ws_size,
                              hipStream_t stream) {
    const float* seq  = (const float*)d_in[0];
    const float* tgt  = (const float*)d_in[1];
    const int*   mask = (const int*)d_in[2];
    const float* w1   = (const float*)d_in[3];
    const float* b1   = (const float*)d_in[4];
    const float* w2   = (const float*)d_in[5];
    const float* b2   = (const float*)d_in[6];
    float* out = (float*)d_out;
    attn_fused<<<dim3(NB), dim3(256), 0, stream>>>(seq, tgt, mask, w1, b1, w2, b2, out);
}